// Round 1
// baseline (257.934 us; speedup 1.0000x reference)
//
#include <hip/hip_runtime.h>

// CNF ODE integration, one wave (64 lanes) per batch element, fixed-step RK4.
// B=512, D=32, H=256. State per element: x[32] (lanes 0..31), dlogp (lane 32),
// loss (lane 33). Weights held entirely in VGPRs (~260 regs/lane), LDS only
// used as a tiny cross-lane exchange buffer. No block-wide sync cost: blocks
// are single-wave, so __syncthreads() is effectively waitcnt-only.

typedef float f4 __attribute__((ext_vector_type(4)));

#define NSTEP 32   // RK4 steps; (L*h)^4 error ~1e-4 << 0.88 threshold

__global__ __launch_bounds__(64, 1)
void cnf_kernel(const float* __restrict__ X0,
                const float* __restrict__ W1,   // (33,256) row-major
                const float* __restrict__ B1,   // (256,)
                const float* __restrict__ W2,   // (256,32) row-major
                const float* __restrict__ B2,   // (32,)
                float* __restrict__ out)        // 512*32 + 512 + 512
{
    const int lane = threadIdx.x;   // 0..63
    const int b    = blockIdx.x;    // batch element
    const int u    = lane & 7;      // output-column group: owns f[4u..4u+3]
    const int r    = lane >> 3;     // hidden-row group: owns h in [32r,32r+32)

    __shared__ float sx[32];
    __shared__ float sh[256];
    __shared__ float sf[32];

    // ---- weights -> registers (resident for whole kernel) ----
    // W1 slice: rows i=0..32, cols 4*lane..4*lane+3  (33 f4 = 132 VGPRs)
    f4 w1r[33];
    const f4* W1v = (const f4*)W1;
#pragma unroll
    for (int i = 0; i < 33; ++i) w1r[i] = W1v[i * 64 + lane];

    // W2 slice: rows 32r..32r+31, cols 4u..4u+3  (32 f4 = 128 VGPRs)
    f4 w2r[32];
    const f4* W2v = (const f4*)W2;
#pragma unroll
    for (int j = 0; j < 32; ++j) w2r[j] = W2v[(32 * r + j) * 8 + u];

    const f4 b1r = ((const f4*)B1)[lane];
    const f4 b2r = ((const f4*)B2)[u];

    // ---- c_h = sum_{i<32} W1[i,h] * W2[h,i], h = 4*lane+q (exact trace) ----
    f4 cr;
#pragma unroll
    for (int q = 0; q < 4; ++q) {
        const int h = 4 * lane + q;
        float cc = 0.f;
#pragma unroll
        for (int i = 0; i < 32; ++i)
            cc = fmaf(w1r[i][q], W2[h * 32 + i], cc);
        cr[q] = cc;
    }

    // ---- initial state (lane s owns state component s) ----
    float st = 0.f;
    if (lane < 32) st = X0[b * 32 + lane];
    // lane 32 (dlogp) and lane 33 (loss) start at 0

    const float dt = 1.0f / (float)NSTEP;

    // one RHS evaluation at y = st + a*kprev, time te; returns k for own comp
    auto eval = [&](float a, float kprev, float te) -> float {
        const float y = st + a * kprev;        // meaningful for lanes < 32
        if (lane < 32) sx[lane] = y;
        __syncthreads();

        // broadcast x into registers
        f4 xv[8];
        const f4* sx4 = (const f4*)sx;
#pragma unroll
        for (int jj = 0; jj < 8; ++jj) xv[jj] = sx4[jj];

        // hidden layer: z_h for h = 4*lane+{0..3}
        f4 z = b1r;
#pragma unroll
        for (int jj = 0; jj < 8; ++jj)
#pragma unroll
            for (int c = 0; c < 4; ++c)
                z += xv[jj][c] * w1r[4 * jj + c];
        z += te * w1r[32];

        f4 hv;
        hv.x = tanhf(z.x); hv.y = tanhf(z.y);
        hv.z = tanhf(z.z); hv.w = tanhf(z.w);
        ((f4*)sh)[lane] = hv;

        float dv = (1.f - hv.x * hv.x) * cr.x + (1.f - hv.y * hv.y) * cr.y
                 + (1.f - hv.z * hv.z) * cr.z + (1.f - hv.w * hv.w) * cr.w;
        float sq = (lane < 32) ? y * y : 0.f;
        __syncthreads();

        // output layer: partial f[4u..4u+3] over h in [32r, 32r+32)
        f4 acc = {0.f, 0.f, 0.f, 0.f};
        const f4* sh4 = (const f4*)sh;
#pragma unroll
        for (int jj = 0; jj < 8; ++jj) {
            const f4 hb = sh4[8 * r + jj];
#pragma unroll
            for (int c = 0; c < 4; ++c)
                acc += hb[c] * w2r[4 * jj + c];
        }
        // reduce the 8 r-replicas (butterfly over lanes sharing u)
#pragma unroll
        for (int off = 8; off < 64; off <<= 1) {
            acc.x += __shfl_xor(acc.x, off);
            acc.y += __shfl_xor(acc.y, off);
            acc.z += __shfl_xor(acc.z, off);
            acc.w += __shfl_xor(acc.w, off);
        }
        if (lane < 8) {
            f4 fv = acc + b2r;
            ((f4*)sf)[u] = fv;
        }
        // full-wave reductions for divergence and ||x||^2
#pragma unroll
        for (int off = 1; off < 64; off <<= 1) {
            dv += __shfl_xor(dv, off);
            sq += __shfl_xor(sq, off);
        }
        __syncthreads();

        float k = 0.f;
        if (lane < 32)       k = sf[lane];
        else if (lane == 32) k = -dv;
        else if (lane == 33) k = 0.5f * sq;
        return k;
    };

    for (int step = 0; step < NSTEP; ++step) {
        const float t0 = (float)step * dt;
        const float th = t0 + 0.5f * dt;
        const float t1 = t0 + dt;
        const float k1 = eval(0.f,       0.f, t0);
        const float k2 = eval(0.5f * dt, k1,  th);
        const float k3 = eval(0.5f * dt, k2,  th);
        const float k4 = eval(dt,        k3,  t1);
        st += (dt * (1.f / 6.f)) * (k1 + 2.f * k2 + 2.f * k3 + k4);
    }

    // output: x (B,32) row-major, then dlogp (B,), then loss (B,)
    if (lane < 32)       out[b * 32 + lane]      = st;
    else if (lane == 32) out[512 * 32 + b]       = st;
    else if (lane == 33) out[512 * 32 + 512 + b] = st;
}

extern "C" void kernel_launch(void* const* d_in, const int* in_sizes, int n_in,
                              void* d_out, int out_size, void* d_ws, size_t ws_size,
                              hipStream_t stream) {
    const float* x  = (const float*)d_in[0];
    const float* W1 = (const float*)d_in[1];
    const float* b1 = (const float*)d_in[2];
    const float* W2 = (const float*)d_in[3];
    const float* b2 = (const float*)d_in[4];
    float* out = (float*)d_out;
    hipLaunchKernelGGL(cnf_kernel, dim3(512), dim3(64), 0, stream,
                       x, W1, b1, W2, b2, out);
}